// Round 3
// baseline (584.136 us; speedup 1.0000x reference)
//
#include <hip/hip_runtime.h>

// Problem constants (ScaledDotProductAttention: B=16, S=2048, D=64, T=8)
constexpr int NB = 16;
constexpr int NS = 2048;
constexpr int ND = 64;
constexpr int MTILE = 32;              // query rows per block

typedef __attribute__((ext_vector_type(8))) short bh8;     // 8 x bf16 bits (4 VGPRs)
typedef __attribute__((ext_vector_type(4))) float f32x4;   // MFMA accumulator

constexpr int EB_STRIDE = 2048 + 8;    // bf16/row: 4112B = 257*16 (16B align kept, pow2 bank stride broken)
constexpr int VT_STRIDE = 128 + 8;     // bf16/row: 272B = 17*16

__device__ __forceinline__ unsigned short f2bf(float x) {
  unsigned u = __float_as_uint(x);
  u += 0x7fffu + ((u >> 16) & 1u);     // round-to-nearest-even
  return (unsigned short)(u >> 16);
}
__device__ __forceinline__ float bf2f(unsigned u16) {
  return __uint_as_float(u16 << 16);
}

// 1024 threads = 16 waves/CU (4/SIMD) — latency hiding was the R2 bottleneck
// (Occupancy 24%, VALU 16%, MFMA 2%, HBM 15% -> nothing saturated).
__global__ __launch_bounds__(1024, 1)
void sdpa_fused_kernel(const float* __restrict__ q, const float* __restrict__ k,
                       const float* __restrict__ v, const int* __restrict__ mask,
                       float* __restrict__ outO, float* __restrict__ outA)
{
  extern __shared__ char smem[];
  unsigned short* ebuf  = (unsigned short*)smem;            // [32][EB_STRIDE] bf16 e=exp(s)
  unsigned short* vbufT = ebuf + MTILE * EB_STRIDE;         // [64][VT_STRIDE] bf16 V^T tile (128 key slots)
  float* rowsumP = (float*)(vbufT + 64 * VT_STRIDE);        // [32][8] partial row sums
  float* invl    = rowsumP + 32 * 8;                        // [32]
  float* osum    = (float*)vbufT;                           // phase-3 reduce scratch (aliases vbufT, 8KB)

  const int tid  = threadIdx.x;
  const int wave = tid >> 6;
  const int lane = tid & 63;
  const int n16  = lane & 15;
  const int quad = lane >> 4;
  const int b     = blockIdx.y;
  const int mbase = blockIdx.x * MTILE;

  // ---- Phase 1: 16 waves = (row half) x (8 chunks of 256 keys)
  const int mrow0 = (wave & 1) * 16;
  const int chunk = wave >> 1;           // 0..7
  const int col0  = chunk * 256;

  // Q fragment (A-operand: lane holds A[m=lane&15][k=quad*8+j]), pre-scaled by 1/8
  bh8 aq[2];
  {
    const float* qp = q + ((long)(b * NS + mbase + mrow0 + n16)) * ND + quad * 8;
    #pragma unroll
    for (int kk = 0; kk < 2; ++kk) {
      float4 x0 = *(const float4*)(qp + kk * 32);
      float4 x1 = *(const float4*)(qp + kk * 32 + 4);
      bh8 f;
      f[0] = f2bf(x0.x * 0.125f); f[1] = f2bf(x0.y * 0.125f);
      f[2] = f2bf(x0.z * 0.125f); f[3] = f2bf(x0.w * 0.125f);
      f[4] = f2bf(x1.x * 0.125f); f[5] = f2bf(x1.y * 0.125f);
      f[6] = f2bf(x1.z * 0.125f); f[7] = f2bf(x1.w * 0.125f);
      aq[kk] = f;
    }
  }

  // S = (Q/8)K^T via MFMA; e = mask ? exp(s) : 0 -> ebuf; accumulate row sums.
  float rsum[4] = {0.f, 0.f, 0.f, 0.f};
  #pragma unroll 2
  for (int nt = 0; nt < 16; ++nt) {
    const int key = col0 + nt * 16 + n16;  // B-operand: lane holds B[k=quad*8+j][n=lane&15]=K[key][kdim]
    const float* kp = k + ((long)(b * NS + key)) * ND + quad * 8;
    f32x4 acc = {0.f, 0.f, 0.f, 0.f};
    #pragma unroll
    for (int kk = 0; kk < 2; ++kk) {
      float4 x0 = *(const float4*)(kp + kk * 32);
      float4 x1 = *(const float4*)(kp + kk * 32 + 4);
      bh8 f;
      f[0] = f2bf(x0.x); f[1] = f2bf(x0.y); f[2] = f2bf(x0.z); f[3] = f2bf(x0.w);
      f[4] = f2bf(x1.x); f[5] = f2bf(x1.y); f[6] = f2bf(x1.z); f[7] = f2bf(x1.w);
      acc = __builtin_amdgcn_mfma_f32_16x16x32_bf16(aq[kk], f, acc, 0, 0, 0);
    }
    // C/D layout: col = lane&15 (== key), row = quad*4 + r
    #pragma unroll
    for (int r = 0; r < 4; ++r) {
      const int lrow = mrow0 + quad * 4 + r;
      const int grow = mbase + lrow;
      const int m = mask[(long)grow * NS + key];
      const float e = m ? __expf(acc[r]) : 0.f;
      rsum[r] += e;
      ebuf[lrow * EB_STRIDE + key] = f2bf(e);
    }
  }

  #pragma unroll
  for (int r = 0; r < 4; ++r) {
    float s = rsum[r];
    s += __shfl_xor(s, 1);
    s += __shfl_xor(s, 2);
    s += __shfl_xor(s, 4);
    s += __shfl_xor(s, 8);
    if (n16 == 0) rowsumP[(mrow0 + quad * 4 + r) * 8 + chunk] = s;
  }
  __syncthreads();
  if (tid < 32) {
    float l = 0.f;
    #pragma unroll
    for (int c = 0; c < 8; ++c) l += rowsumP[tid * 8 + c];
    invl[tid] = 1.f / l;
  }
  __syncthreads();

  // ---- Phase 2: attn = e * invl -> global (2 rows per iteration, float4-coalesced)
  {
    float* aout = outA + ((long)(b * NS + mbase)) * NS;
    const int r2 = tid >> 9;               // 0..1
    const int c4 = (tid & 511) * 4;        // column (floats)
    #pragma unroll 2
    for (int it = 0; it < 32; it += 2) {
      const int row = it + r2;
      const float il = invl[row];
      uint2 raw = *(const uint2*)(ebuf + row * EB_STRIDE + c4);
      float4 o;
      o.x = bf2f(raw.x & 0xffffu) * il;
      o.y = bf2f(raw.x >> 16)     * il;
      o.z = bf2f(raw.y & 0xffffu) * il;
      o.w = bf2f(raw.y >> 16)     * il;
      *(float4*)(aout + (long)row * NS + c4) = o;
    }
  }

  // ---- Phase 3: O = P V via MFMA, K-split across wave pairs.
  // tile = wave&7 -> (mtile 16 rows, dtile 16 cols); khalf = wave>>3 -> keys [khalf*1024, +1024)
  const int tile  = wave & 7;
  const int mtile = tile & 1;
  const int dtile = tile >> 1;
  const int khalf = wave >> 3;
  const int kbase = khalf * 1024;
  const int s128  = tid & 127;             // V staging slot
  const int g     = tid >> 7;              // 0..7
  const int skey0 = (s128 >> 6) * 1024 + (s128 & 63);  // slot -> key offset (both halves staged)
  f32x4 oacc = {0.f, 0.f, 0.f, 0.f};
  for (int c = 0; c < 16; ++c) {           // 64 keys per half per iteration (128 staged)
    __syncthreads();                       // previous chunk's vbufT readers done
    {
      const float4* vsrc = (const float4*)(v + ((long)(b * NS) + c * 64 + skey0) * ND);
      #pragma unroll
      for (int i = 0; i < 2; ++i) {
        const int dcol4 = g + 8 * i;       // which float4 within the V row
        float4 vv = vsrc[dcol4];
        const int d0 = dcol4 * 4;
        vbufT[(d0 + 0) * VT_STRIDE + s128] = f2bf(vv.x);
        vbufT[(d0 + 1) * VT_STRIDE + s128] = f2bf(vv.y);
        vbufT[(d0 + 2) * VT_STRIDE + s128] = f2bf(vv.z);
        vbufT[(d0 + 3) * VT_STRIDE + s128] = f2bf(vv.w);
      }
    }
    __syncthreads();
    #pragma unroll
    for (int kt = 0; kt < 2; ++kt) {
      bh8 af = *(const bh8*)(ebuf  + (mtile * 16 + n16) * EB_STRIDE + kbase + c * 64 + kt * 32 + quad * 8);
      bh8 bf = *(const bh8*)(vbufT + (dtile * 16 + n16) * VT_STRIDE + khalf * 64 + kt * 32 + quad * 8);
      oacc = __builtin_amdgcn_mfma_f32_16x16x32_bf16(af, bf, oacc, 0, 0, 0);
    }
  }
  // reduce the two K-halves via LDS scratch (aliases vbufT — all readers done after barrier)
  __syncthreads();
  if (khalf == 1) *(f32x4*)(osum + tile * 256 + lane * 4) = oacc;
  __syncthreads();
  if (khalf == 0) {
    f32x4 other = *(const f32x4*)(osum + tile * 256 + lane * 4);
    #pragma unroll
    for (int r = 0; r < 4; ++r) {
      const int lrow = mtile * 16 + quad * 4 + r;
      outO[((long)(b * NS + mbase + lrow)) * ND + dtile * 16 + n16] =
          (oacc[r] + other[r]) * invl[lrow];
    }
  }
}

extern "C" void kernel_launch(void* const* d_in, const int* in_sizes, int n_in,
                              void* d_out, int out_size, void* d_ws, size_t ws_size,
                              hipStream_t stream) {
  const float* q    = (const float*)d_in[0];
  const float* k    = (const float*)d_in[1];
  const float* v    = (const float*)d_in[2];
  const int*   mask = (const int*)d_in[3];
  float* outO = (float*)d_out;                      // [16,2048,64]
  float* outA = outO + (long)NB * NS * ND;          // [16,2048,2048]

  const size_t lds = (size_t)(MTILE * EB_STRIDE + 64 * VT_STRIDE) * sizeof(short)
                   + (size_t)(32 * 8 + 32) * sizeof(float);
  hipFuncSetAttribute((const void*)sdpa_fused_kernel,
                      hipFuncAttributeMaxDynamicSharedMemorySize, (int)lds);
  dim3 grid(NS / MTILE, NB);
  sdpa_fused_kernel<<<grid, 1024, lds, stream>>>(q, k, v, mask, outO, outA);
}

// Round 4
// 501.621 us; speedup vs baseline: 1.1645x; 1.1645x over previous
//
#include <hip/hip_runtime.h>

// ScaledDotProductAttention: B=16, S=2048, D=64, T=8
constexpr int NB = 16;
constexpr int NS = 2048;
constexpr int ND = 64;
constexpr int MTILE = 16;              // query rows per block (16 -> 2 blocks/CU)

typedef __attribute__((ext_vector_type(8))) short bh8;            // 8 x bf16 (4 VGPRs)
typedef __attribute__((ext_vector_type(4))) float f32x4;          // MFMA accumulator
typedef __attribute__((ext_vector_type(4))) unsigned short us4;   // 4 x bf16 store

constexpr int EB_STRIDE = 2048 + 8;    // bf16/row: 4112B = 257*16 (16B align kept, pow2 bank stride broken)

__device__ __forceinline__ unsigned short f2bf(float x) {
  unsigned u = __float_as_uint(x);
  u += 0x7fffu + ((u >> 16) & 1u);     // round-to-nearest-even
  return (unsigned short)(u >> 16);
}
__device__ __forceinline__ float bf2f(unsigned u16) {
  return __uint_as_float(u16 << 16);
}

// ---- Kernel 0: Vt[b][d][k] = bf16(V[b][k][d]) — makes the PV B-fragment a single
// contiguous 16B global load (L2-hot, 256KB/batch), eliminating phase-3 LDS staging.
__global__ __launch_bounds__(256)
void vtrans_kernel(const float* __restrict__ v, unsigned short* __restrict__ vt) {
  __shared__ float tile[64][65];
  const int b   = blockIdx.y;
  const int kc  = blockIdx.x;          // 64-key chunk
  const int tid = threadIdx.x;
  const int r0  = tid >> 4;            // 0..15
  const int c0  = (tid & 15) * 4;      // 0..60
  #pragma unroll
  for (int p = 0; p < 4; ++p) {
    const int krow = p * 16 + r0;
    float4 vv = *(const float4*)(v + ((long)(b * NS) + kc * 64 + krow) * ND + c0);
    tile[c0 + 0][krow] = vv.x;
    tile[c0 + 1][krow] = vv.y;
    tile[c0 + 2][krow] = vv.z;
    tile[c0 + 3][krow] = vv.w;
  }
  __syncthreads();
  #pragma unroll
  for (int p = 0; p < 4; ++p) {
    const int d = p * 16 + r0;
    us4 o;
    o.x = f2bf(tile[d][c0 + 0]);
    o.y = f2bf(tile[d][c0 + 1]);
    o.z = f2bf(tile[d][c0 + 2]);
    o.w = f2bf(tile[d][c0 + 3]);
    *(us4*)(vt + ((long)(b * 64 + d)) * NS + kc * 64 + c0) = o;
  }
}

// ---- Kernel 1: fused scores+softmax+attn-write+PV. 512 threads, 70.5KB LDS -> 2 blocks/CU
// (two independent barrier domains per CU was the R3 lesson: occupancy inside ONE barrier
// domain doesn't hide barrier stalls).
__global__ __launch_bounds__(512, 1)
void sdpa_fused_kernel(const float* __restrict__ q, const float* __restrict__ k,
                       const int* __restrict__ mask, const unsigned short* __restrict__ vt,
                       float* __restrict__ outO, float* __restrict__ outA)
{
  extern __shared__ char smem[];
  unsigned short* ebuf = (unsigned short*)smem;       // [16][EB_STRIDE] bf16 e=exp(s)
  float* rowsumP = (float*)(ebuf + MTILE * EB_STRIDE);// [16][8] partial row sums
  float* invl    = rowsumP + 16 * 8;                  // [16]
  float* osum    = invl + 16;                         // [4][64][4] phase-3 K-half reduce

  const int tid  = threadIdx.x;
  const int wave = tid >> 6;
  const int lane = tid & 63;
  const int n16  = lane & 15;
  const int quad = lane >> 4;
  const int b     = blockIdx.y;
  const int mbase = blockIdx.x * MTILE;

  // ---- Phase 1: 8 waves x 256-key chunks. All waves share the same 16 query rows.
  const int col0 = wave * 256;

  // Q fragment (A-operand: lane holds A[m=lane&15][k=quad*8+j]), pre-scaled by 1/8
  bh8 aq[2];
  {
    const float* qp = q + ((long)(b * NS + mbase + n16)) * ND + quad * 8;
    #pragma unroll
    for (int kk = 0; kk < 2; ++kk) {
      float4 x0 = *(const float4*)(qp + kk * 32);
      float4 x1 = *(const float4*)(qp + kk * 32 + 4);
      bh8 f;
      f[0] = f2bf(x0.x * 0.125f); f[1] = f2bf(x0.y * 0.125f);
      f[2] = f2bf(x0.z * 0.125f); f[3] = f2bf(x0.w * 0.125f);
      f[4] = f2bf(x1.x * 0.125f); f[5] = f2bf(x1.y * 0.125f);
      f[6] = f2bf(x1.z * 0.125f); f[7] = f2bf(x1.w * 0.125f);
      aq[kk] = f;
    }
  }

  // S = (Q/8)K^T via MFMA; e = mask ? exp(s) : 0 -> ebuf; accumulate row sums.
  float rsum[4] = {0.f, 0.f, 0.f, 0.f};
  #pragma unroll 2
  for (int nt = 0; nt < 16; ++nt) {
    const int key = col0 + nt * 16 + n16;  // B-operand: lane holds B[k=quad*8+j][n=lane&15]=K[key][kdim]
    const float* kp = k + ((long)(b * NS + key)) * ND + quad * 8;
    f32x4 acc = {0.f, 0.f, 0.f, 0.f};
    #pragma unroll
    for (int kk = 0; kk < 2; ++kk) {
      float4 x0 = *(const float4*)(kp + kk * 32);
      float4 x1 = *(const float4*)(kp + kk * 32 + 4);
      bh8 f;
      f[0] = f2bf(x0.x); f[1] = f2bf(x0.y); f[2] = f2bf(x0.z); f[3] = f2bf(x0.w);
      f[4] = f2bf(x1.x); f[5] = f2bf(x1.y); f[6] = f2bf(x1.z); f[7] = f2bf(x1.w);
      acc = __builtin_amdgcn_mfma_f32_16x16x32_bf16(aq[kk], f, acc, 0, 0, 0);
    }
    // C/D layout: col = lane&15 (== key), row = quad*4 + r
    #pragma unroll
    for (int r = 0; r < 4; ++r) {
      const int lrow = quad * 4 + r;
      const int grow = mbase + lrow;
      const int m = mask[(long)grow * NS + key];
      const float e = m ? __expf(acc[r]) : 0.f;
      rsum[r] += e;
      ebuf[lrow * EB_STRIDE + key] = f2bf(e);
    }
  }

  #pragma unroll
  for (int r = 0; r < 4; ++r) {
    float s = rsum[r];
    s += __shfl_xor(s, 1);
    s += __shfl_xor(s, 2);
    s += __shfl_xor(s, 4);
    s += __shfl_xor(s, 8);
    if (n16 == 0) rowsumP[(quad * 4 + r) * 8 + wave] = s;
  }
  __syncthreads();
  if (tid < 16) {
    float l = 0.f;
    #pragma unroll
    for (int c = 0; c < 8; ++c) l += rowsumP[tid * 8 + c];
    invl[tid] = 1.f / l;
  }
  __syncthreads();

  // ---- Phase 2: attn = e * invl -> global (one row / iteration, float4-coalesced)
  {
    float* aout = outA + ((long)(b * NS + mbase)) * NS;
    const int c4 = tid * 4;
    #pragma unroll 2
    for (int row = 0; row < MTILE; ++row) {
      const float il = invl[row];
      uint2 raw = *(const uint2*)(ebuf + row * EB_STRIDE + c4);
      float4 o;
      o.x = bf2f(raw.x & 0xffffu) * il;
      o.y = bf2f(raw.x >> 16)     * il;
      o.z = bf2f(raw.y & 0xffffu) * il;
      o.w = bf2f(raw.y >> 16)     * il;
      *(float4*)(aout + (long)row * NS + c4) = o;
    }
  }

  // ---- Phase 3: O = P V via MFMA. B-fragment = 16B contiguous load from Vt (L2-hot).
  // ZERO barriers in the loop. 8 waves = 4 d-tiles x 2 K-halves.
  const int dtile = wave & 3;
  const int khalf = wave >> 2;
  const int kbase = khalf * 1024;
  const unsigned short* vrow = vt + ((long)(b * 64 + dtile * 16 + n16)) * NS + kbase + quad * 8;
  f32x4 oacc = {0.f, 0.f, 0.f, 0.f};
  #pragma unroll 4
  for (int kc = 0; kc < 32; ++kc) {
    const int k0 = kbase + kc * 32;
    bh8 af = *(const bh8*)(ebuf + n16 * EB_STRIDE + k0 + quad * 8);
    bh8 bf = *(const bh8*)(vrow + kc * 32);
    oacc = __builtin_amdgcn_mfma_f32_16x16x32_bf16(af, bf, oacc, 0, 0, 0);
  }
  // K-half reduce via LDS, then scale by invl and store O.
  if (khalf == 1) *(f32x4*)(osum + (dtile * 64 + lane) * 4) = oacc;
  __syncthreads();
  if (khalf == 0) {
    f32x4 other = *(const f32x4*)(osum + (dtile * 64 + lane) * 4);
    #pragma unroll
    for (int r = 0; r < 4; ++r) {
      const int lrow = quad * 4 + r;   // C/D: col = n16 (d), row = quad*4+r (query row)
      outO[((long)(b * NS + mbase + lrow)) * ND + dtile * 16 + n16] =
          (oacc[r] + other[r]) * invl[lrow];
    }
  }
}

extern "C" void kernel_launch(void* const* d_in, const int* in_sizes, int n_in,
                              void* d_out, int out_size, void* d_ws, size_t ws_size,
                              hipStream_t stream) {
  const float* q    = (const float*)d_in[0];
  const float* k    = (const float*)d_in[1];
  const float* v    = (const float*)d_in[2];
  const int*   mask = (const int*)d_in[3];
  float* outO = (float*)d_out;                      // [16,2048,64]
  float* outA = outO + (long)NB * NS * ND;          // [16,2048,2048]
  unsigned short* vt = (unsigned short*)d_ws;       // [16][64][2048] bf16 V^T

  vtrans_kernel<<<dim3(NS / 64, NB), 256, 0, stream>>>(v, vt);

  const size_t lds = (size_t)(MTILE * EB_STRIDE) * sizeof(short)
                   + (size_t)(16 * 8 + 16 + 4 * 64 * 4) * sizeof(float);
  hipFuncSetAttribute((const void*)sdpa_fused_kernel,
                      hipFuncAttributeMaxDynamicSharedMemorySize, (int)lds);
  sdpa_fused_kernel<<<dim3(NS / MTILE, NB), 512, lds, stream>>>(q, k, mask, vt, outO, outA);
}